// Round 1
// baseline (1347.769 us; speedup 1.0000x reference)
//
#include <hip/hip_runtime.h>
#include <hip/hip_bf16.h>

#define D_MODEL 1024
#define HIDDEN  4096
#define NTOK    16384
#define HP      12288   // shared + expert0 + expert1 hidden rows in W1t / cols in W2t
#define GPAD    16640   // 65 * 256 padded grouped-token space (256-granular)

typedef __hip_bfloat16 bf16;
typedef __attribute__((ext_vector_type(8))) short short8;
typedef __attribute__((ext_vector_type(4))) float floatx4;

struct bf16x4 { bf16 a, b, c, d; };

__device__ inline void gload_lds16(const bf16* g, bf16* l) {
    __builtin_amdgcn_global_load_lds(
        (const __attribute__((address_space(1))) void*)g,
        (__attribute__((address_space(3))) void*)l, 16, 0, 0);
}

// ---------------------------------------------------------------------------
// prep: b1_all = [sb1 | b1_0 | b1_1] (fp32); addvec[e] init = b2_0 + b2_1;
// cnt = 0.
// ---------------------------------------------------------------------------
__global__ void prep_small(const float* __restrict__ sb1, const float* __restrict__ b1,
                           const float* __restrict__ b2,
                           float* __restrict__ b1_all, float* __restrict__ addvec,
                           int* __restrict__ cnt)
{
    int i = blockIdx.x * 256 + threadIdx.x;   // 0..12287
    b1_all[i] = (i < HIDDEN) ? sb1[i] : b1[i - HIDDEN];
    if (i < D_MODEL) {
        float s = b2[i] + b2[D_MODEL + i];
        addvec[i] = s;
        addvec[D_MODEL + i] = s;
    }
    if (i < 2) cnt[i] = 0;
}

// ---------------------------------------------------------------------------
// addvec[1-e][d] += sum_h relu(b1[e][h]) * w2[e][h][d]
// ---------------------------------------------------------------------------
__global__ void addvec_accum(const float* __restrict__ b1, const float* __restrict__ w2,
                             float* __restrict__ addvec)
{
    const int blk  = blockIdx.x;
    const int e    = blk >> 6;
    const int hseg = (blk >> 2) & 15;
    const int d    = (blk & 3) * 256 + threadIdx.x;
    const float* B1 = b1 + e * HIDDEN + hseg * 256;
    const float* W  = w2 + (size_t)e * HIDDEN * D_MODEL + (size_t)hseg * 256 * D_MODEL + d;
    float s = 0.f;
    for (int h = 0; h < 256; ++h) {
        float b = B1[h]; b = b > 0.f ? b : 0.f;
        s += b * W[(size_t)h * D_MODEL];
    }
    atomicAdd(&addvec[(1 - e) * D_MODEL + d], s);
}

// ---------------------------------------------------------------------------
// 32x32 tiled transpose + fp32->bf16 cast:  dst[c][r] = (bf16)src[r][c]
// ---------------------------------------------------------------------------
__global__ void transpose_cast(const float* __restrict__ src, bf16* __restrict__ dst,
                               int R, int Cc, int ldDst)
{
    __shared__ float tile[32][33];
    const int bx = blockIdx.x * 32;
    const int by = blockIdx.y * 32;
    const int tx = threadIdx.x & 31;
    const int ty = threadIdx.x >> 5;
#pragma unroll
    for (int i = 0; i < 32; i += 8)
        tile[ty + i][tx] = src[(size_t)(by + ty + i) * Cc + bx + tx];
    __syncthreads();
#pragma unroll
    for (int i = 0; i < 32; i += 8)
        dst[(size_t)(bx + ty + i) * ldDst + by + tx] = __float2bfloat16(tile[tx][ty + i]);
}

// ---------------------------------------------------------------------------
// Gating (fp32, argmax == softmax-top1) + x cast to bf16 + group position.
// ---------------------------------------------------------------------------
__global__ void gate_route_cast(const float* __restrict__ x, const float* __restrict__ gw,
                                int* __restrict__ route, int* __restrict__ pos,
                                int* __restrict__ cnt, bf16* __restrict__ Xb)
{
    const int token = blockIdx.x * 4 + (threadIdx.x >> 6);
    const int lane  = threadIdx.x & 63;
    const float4* xr = (const float4*)(x + (size_t)token * D_MODEL);
    const float4* g0 = (const float4*)gw;
    const float4* g1 = (const float4*)(gw + D_MODEL);
    bf16x4* xo = (bf16x4*)(Xb + (size_t)token * D_MODEL);
    float s0 = 0.f, s1 = 0.f;
    for (int i = lane; i < D_MODEL / 4; i += 64) {
        float4 v = xr[i];
        float4 a = g0[i], b = g1[i];
        s0 += v.x * a.x + v.y * a.y + v.z * a.z + v.w * a.w;
        s1 += v.x * b.x + v.y * b.y + v.z * b.z + v.w * b.w;
        bf16x4 o = { __float2bfloat16(v.x), __float2bfloat16(v.y),
                     __float2bfloat16(v.z), __float2bfloat16(v.w) };
        xo[i] = o;
    }
#pragma unroll
    for (int off = 32; off > 0; off >>= 1) {
        s0 += __shfl_down(s0, off, 64);
        s1 += __shfl_down(s1, off, 64);
    }
    if (lane == 0) {
        int r = (s1 > s0) ? 1 : 0;
        route[token] = r;
        pos[token] = atomicAdd(&cnt[r], 1);
    }
}

// gperm init + per-256-row-block expert id.  off1 = ceil(count0/256)*256.
__global__ void k_init(const int* __restrict__ cnt, int* __restrict__ gperm,
                       int* __restrict__ blkexp)
{
    int i = blockIdx.x * 256 + threadIdx.x;   // 0..GPAD-1
    int off1 = ((cnt[0] + 255) >> 8) << 8;
    if (i < GPAD) gperm[i] = -1;
    if (i < GPAD / 256) blkexp[i] = (i * 256 >= off1) ? 1 : 0;
}

__global__ void k_scatter(const int* __restrict__ route, const int* __restrict__ pos,
                          const int* __restrict__ cnt, int* __restrict__ gperm)
{
    int t = blockIdx.x * 256 + threadIdx.x;   // 0..NTOK-1
    int off1 = ((cnt[0] + 255) >> 8) << 8;
    int g = route[t] ? off1 + pos[t] : pos[t];
    gperm[g] = t;
}

// Xg[g] = Xb[gperm[g]] or 0.
__global__ void gather_xg(const bf16* __restrict__ Xb, const int* __restrict__ gperm,
                          bf16* __restrict__ Xg)
{
    const int g = blockIdx.x * 2 + (threadIdx.x >> 7);
    const int l = threadIdx.x & 127;
    const int t = gperm[g];
    float4* dst = (float4*)(Xg + (size_t)g * D_MODEL);
    if (t >= 0) {
        const float4* src = (const float4*)(Xb + (size_t)t * D_MODEL);
        dst[l] = src[l];
    } else {
        dst[l] = make_float4(0.f, 0.f, 0.f, 0.f);
    }
}

// ---------------------------------------------------------------------------
// 256x256 bf16 GEMM:  C[M,N] = A[M,K] @ B[N,K]^T (row stride ldb)
// BK=64, 8 waves (2Mx4N, each 128x64 out), 128 KiB LDS double buffer.
// Depth-2 pipeline: counted s_waitcnt vmcnt(8) across raw s_barriers (T4);
// stage tile t+2 into the buffer just consumed (race-free: after barrier 2).
// LDS XOR-swizzle (T2) via pre-swizzled GLOBAL source + swizzled read
// (involution p ^= ((p>>7)&7)<<4 : 16B-granule-preserving).
// setprio around MFMA clusters (T5).
// MODE 0: shared GEMM1 -> H (bf16 relu);  MODE 1: shared GEMM2 -> out (fp32)
// MODE 2: grouped GEMM1 -> H;             MODE 3: grouped GEMM2 scatter-add
// ---------------------------------------------------------------------------
template <int MODE>
__global__ __launch_bounds__(512, 2) void gemm256(
    const bf16* __restrict__ A, const bf16* __restrict__ B,
    void* __restrict__ Cout, const float* __restrict__ bias,
    const int* __restrict__ blkexp, const int* __restrict__ gperm,
    int M, int N, int K, int ldb)
{
    __shared__ bf16 smem[2 * 2 * 16384];          // [buf][A|B][256*64] = 128 KiB
    (void)M;
    const int tid  = threadIdx.x;
    const int lane = tid & 63;
    const int wave = tid >> 6;
    const long bm = (long)blockIdx.y * 256;
    const long bn = (long)blockIdx.x * 256;

    long bOff = 0;
    const float* biasP = bias;
    int e = 0;
    if (MODE == 2) {
        e = blkexp[blockIdx.y];
        bOff = (long)(1 + e) * HIDDEN * ldb;      // W1t expert row section
        biasP = bias + (1 + e) * HIDDEN;
    }
    if (MODE == 3) {
        e = blkexp[blockIdx.y];
        bOff = (long)(1 + e) * HIDDEN;            // W2t expert col section
        biasP = bias + e * D_MODEL;
    }

    // ---- staging: linear LDS dest, pre-swizzled global source ------------
    const int p    = tid * 16;                        // linear byte in first 8KB slab
    const int sp   = p ^ (((p >> 7) & 7) << 4);       // involutive slot swizzle
    const int srow = sp >> 7;                         // 0..63
    const int sce  = (sp & 127) >> 1;                 // element col 0..63
    const bf16* sAp = A + (size_t)(bm + srow) * K + sce;
    const bf16* sBp = B + bOff + (size_t)(bn + srow) * ldb + sce;
    const size_t sAstep = (size_t)64 * K;             // +64 rows per instruction slab
    const size_t sBstep = (size_t)64 * ldb;
    bf16* ldsA = smem + wave * 512;                   // + buf*32768 + i*4096
    bf16* ldsB = smem + 16384 + wave * 512;

    // ---- fragment read addressing (swizzled) -----------------------------
    const int wm  = wave >> 2;                        // 0..1
    const int wn  = wave & 3;                         // 0..3
    const int fr  = lane & 15;
    const int fkb = (lane >> 4) << 4;                 // 0/16/32/48 bytes (8 K-elems)
    const int sx  = (fr & 7) << 4;                    // per-lane swizzle XOR
    const char* sb = (const char*)smem;
    const int aBase = (wm * 128 + fr) * 128;          // byte offset in A region
    const int bBase = 32768 + (wn * 64 + fr) * 128;   // byte offset in buf (B region)

    floatx4 acc[8][4];
#pragma unroll
    for (int i = 0; i < 8; i++)
#pragma unroll
        for (int j = 0; j < 4; j++) acc[i][j] = (floatx4){0.f, 0.f, 0.f, 0.f};

    const int NT = K >> 6;                            // 64-wide K tiles (>= 16 here)

#define STAGE(b) do {                                                         \
    _Pragma("unroll")                                                         \
    for (int i_ = 0; i_ < 4; ++i_) {                                          \
        gload_lds16(sAp + (size_t)i_ * sAstep, ldsA + (b) * 32768 + i_ * 4096); \
        gload_lds16(sBp + (size_t)i_ * sBstep, ldsB + (b) * 32768 + i_ * 4096); \
    }                                                                         \
    sAp += 64; sBp += 64;                                                     \
} while (0)

#define COMPUTE(b) do {                                                       \
    const char* cb_ = sb + (b) * 65536;                                       \
    _Pragma("unroll")                                                         \
    for (int ks_ = 0; ks_ < 2; ++ks_) {                                       \
        const int kx_ = ((ks_ * 64) + fkb) ^ sx;                              \
        short8 af_[8], bf_[4];                                                \
        _Pragma("unroll")                                                     \
        for (int i_ = 0; i_ < 8; ++i_)                                        \
            af_[i_] = *(const short8*)(cb_ + aBase + i_ * 2048 + kx_);        \
        _Pragma("unroll")                                                     \
        for (int j_ = 0; j_ < 4; ++j_)                                        \
            bf_[j_] = *(const short8*)(cb_ + bBase + j_ * 2048 + kx_);        \
        __builtin_amdgcn_s_setprio(1);                                        \
        _Pragma("unroll")                                                     \
        for (int i_ = 0; i_ < 8; ++i_) {                                      \
            _Pragma("unroll")                                                 \
            for (int j_ = 0; j_ < 4; ++j_)                                    \
                acc[i_][j_] = __builtin_amdgcn_mfma_f32_16x16x32_bf16(        \
                    af_[i_], bf_[j_], acc[i_][j_], 0, 0, 0);                  \
        }                                                                     \
        __builtin_amdgcn_s_setprio(0);                                        \
    }                                                                         \
} while (0)

    STAGE(0);                                         // tile 0 -> buf0
    STAGE(1);                                         // tile 1 -> buf1  (16 loads in flight)

    for (int t = 0; t < NT - 2; ++t) {
        asm volatile("s_waitcnt vmcnt(8)" ::: "memory");   // tile t landed (own slice)
        __builtin_amdgcn_s_barrier();                      // ...and everyone else's
        __builtin_amdgcn_sched_barrier(0);
        COMPUTE(t & 1);
        __builtin_amdgcn_sched_barrier(0);
        __builtin_amdgcn_s_barrier();                      // all waves done reading buf
        STAGE(t & 1);                                      // tile t+2 overwrites it
    }
    asm volatile("s_waitcnt vmcnt(8)" ::: "memory");
    __builtin_amdgcn_s_barrier();
    __builtin_amdgcn_sched_barrier(0);
    COMPUTE(NT & 1);                                       // tile NT-2
    asm volatile("s_waitcnt vmcnt(0)" ::: "memory");
    __builtin_amdgcn_s_barrier();
    __builtin_amdgcn_sched_barrier(0);
    COMPUTE((NT - 1) & 1);                                 // tile NT-1

#undef STAGE
#undef COMPUTE

    // epilogue: C/D layout col = lane&15, row = (lane>>4)*4 + reg
    const int rq = (lane >> 4) * 4;
#pragma unroll
    for (int j = 0; j < 4; ++j) {
        const long col = bn + wn * 64 + j * 16 + fr;
        const float bv = biasP[col];
#pragma unroll
        for (int i = 0; i < 8; ++i) {
#pragma unroll
            for (int r = 0; r < 4; ++r) {
                const long row = bm + wm * 128 + i * 16 + rq + r;
                float v = acc[i][j][r] + bv;
                if (MODE == 0 || MODE == 2) {
                    v = v > 0.f ? v : 0.f;
                    ((bf16*)Cout)[row * (long)N + col] = __float2bfloat16(v);
                } else if (MODE == 1) {
                    ((float*)Cout)[row * (long)N + col] = v;
                } else {   // MODE 3: scatter-add
                    const int tt = gperm[row];
                    if (tt >= 0) {
                        float* o = (float*)Cout + (size_t)tt * D_MODEL + col;
                        *o += v;
                    }
                }
            }
        }
    }
}

// ---------------------------------------------------------------------------
extern "C" void kernel_launch(void* const* d_in, const int* in_sizes, int n_in,
                              void* d_out, int out_size, void* d_ws, size_t ws_size,
                              hipStream_t stream)
{
    const float* x   = (const float*)d_in[0];
    const float* gw  = (const float*)d_in[1];
    const float* w1  = (const float*)d_in[2];   // [2, 1024, 4096]
    const float* b1  = (const float*)d_in[3];   // [2, 4096]
    const float* w2  = (const float*)d_in[4];   // [2, 4096, 1024]
    const float* b2  = (const float*)d_in[5];   // [2, 1024]
    const float* sw1 = (const float*)d_in[6];   // [1024, 4096]
    const float* sb1 = (const float*)d_in[7];
    const float* sw2 = (const float*)d_in[8];   // [4096, 1024]
    const float* sb2 = (const float*)d_in[9];
    float* out = (float*)d_out;

    // ---- workspace carve-up ---------------------------------------------
    char* p = (char*)d_ws;
    bf16* Xb      = (bf16*)p;  p += (size_t)NTOK * D_MODEL * 2;    // 32 MB
    bf16* Xg      = (bf16*)p;  p += (size_t)GPAD * D_MODEL * 2;    // 32.5 MB
    bf16* W1t     = (bf16*)p;  p += (size_t)HP * D_MODEL * 2;      // 24 MB  [HP,1024]
    bf16* W2t     = (bf16*)p;  p += (size_t)D_MODEL * HP * 2;      // 24 MB  [1024,HP]
    int*  route   = (int*)p;   p += (size_t)NTOK * 4;
    int*  pos     = (int*)p;   p += (size_t)NTOK * 4;
    int*  gperm   = (int*)p;   p += (size_t)GPAD * 4;
    int*  blkexp  = (int*)p;   p += (size_t)(GPAD / 128) * 4;
    int*  cnt     = (int*)p;   p += 2 * 4;
    float* b1_all = (float*)p; p += (size_t)HP * 4;
    float* addvec = (float*)p; p += (size_t)2 * D_MODEL * 4;
    bf16* H       = (bf16*)p;                                      // rest

    const size_t used_fixed = (size_t)(p - (char*)d_ws);
    const size_t avail = (ws_size > used_fixed) ? (ws_size - used_fixed) : 0;
    long cs = (long)(avail / ((size_t)HIDDEN * 2));   // tokens per H chunk
    cs = (cs / 256) * 256;
    if (cs > GPAD) cs = GPAD;
    if (cs < 256) cs = 256;

    prep_small<<<HP / 256, 256, 0, stream>>>(sb1, b1, b2, b1_all, addvec, cnt);
    addvec_accum<<<128, 256, 0, stream>>>(b1, w2, addvec);

    // W1t rows h: [0,4096)=shared, [4096,8192)=e0, [8192,12288)=e1 ; ld 1024
    transpose_cast<<<dim3(HIDDEN / 32, D_MODEL / 32), 256, 0, stream>>>(
        sw1, W1t, D_MODEL, HIDDEN, D_MODEL);
    transpose_cast<<<dim3(HIDDEN / 32, D_MODEL / 32), 256, 0, stream>>>(
        w1, W1t + (size_t)HIDDEN * D_MODEL, D_MODEL, HIDDEN, D_MODEL);
    transpose_cast<<<dim3(HIDDEN / 32, D_MODEL / 32), 256, 0, stream>>>(
        w1 + (size_t)D_MODEL * HIDDEN, W1t + (size_t)2 * HIDDEN * D_MODEL, D_MODEL, HIDDEN, D_MODEL);
    // W2t [1024 rows, ld HP]: cols [0,4096)=shared, then e0, e1
    transpose_cast<<<dim3(D_MODEL / 32, HIDDEN / 32), 256, 0, stream>>>(
        sw2, W2t, HIDDEN, D_MODEL, HP);
    transpose_cast<<<dim3(D_MODEL / 32, HIDDEN / 32), 256, 0, stream>>>(
        w2, W2t + HIDDEN, HIDDEN, D_MODEL, HP);
    transpose_cast<<<dim3(D_MODEL / 32, HIDDEN / 32), 256, 0, stream>>>(
        w2 + (size_t)HIDDEN * D_MODEL, W2t + (size_t)2 * HIDDEN, HIDDEN, D_MODEL, HP);

    gate_route_cast<<<NTOK / 4, 256, 0, stream>>>(x, gw, route, pos, cnt, Xb);
    k_init<<<(GPAD + 255) / 256, 256, 0, stream>>>(cnt, gperm, blkexp);
    k_scatter<<<NTOK / 256, 256, 0, stream>>>(route, pos, cnt, gperm);
    gather_xg<<<GPAD / 2, 256, 0, stream>>>(Xb, gperm, Xg);

    // ---- shared FFN over all tokens (writes out = shared + sb2) ----------
    for (long t0 = 0; t0 < NTOK; t0 += cs) {
        const long cur = (NTOK - t0 < cs) ? (NTOK - t0) : cs;
        gemm256<0><<<dim3(HIDDEN / 256, cur / 256), 512, 0, stream>>>(
            Xb + t0 * D_MODEL, W1t, H, b1_all, nullptr, nullptr,
            (int)cur, HIDDEN, D_MODEL, D_MODEL);
        gemm256<1><<<dim3(D_MODEL / 256, cur / 256), 512, 0, stream>>>(
            H, W2t, out + t0 * D_MODEL, sb2, nullptr, nullptr,
            (int)cur, D_MODEL, HIDDEN, HP);
    }
    // ---- routed expert over grouped tokens (scatter-add) -----------------
    for (long g0 = 0; g0 < GPAD; g0 += cs) {
        const long cur = (GPAD - g0 < cs) ? (GPAD - g0) : cs;
        gemm256<2><<<dim3(HIDDEN / 256, cur / 256), 512, 0, stream>>>(
            Xg + g0 * D_MODEL, W1t, H, b1_all, blkexp + g0 / 256, nullptr,
            (int)cur, HIDDEN, D_MODEL, D_MODEL);
        gemm256<3><<<dim3(D_MODEL / 256, cur / 256), 512, 0, stream>>>(
            H, W2t, (void*)out, addvec, blkexp + g0 / 256, gperm + g0,
            (int)cur, D_MODEL, HIDDEN, HP);
    }
}

// Round 2
// 1324.089 us; speedup vs baseline: 1.0179x; 1.0179x over previous
//
#include <hip/hip_runtime.h>
#include <hip/hip_bf16.h>

#define D_MODEL 1024
#define HIDDEN  4096
#define NTOK    16384
#define HP      12288   // shared + expert0 + expert1 hidden rows in W1t / cols in W2t
#define GPAD    16640   // 65 * 256 padded grouped-token space (256-granular)

typedef __hip_bfloat16 bf16;
typedef __attribute__((ext_vector_type(8))) short short8;
typedef __attribute__((ext_vector_type(4))) float floatx4;

struct bf16x4 { bf16 a, b, c, d; };

__device__ inline void gload_lds16(const bf16* g, bf16* l) {
    __builtin_amdgcn_global_load_lds(
        (const __attribute__((address_space(1))) void*)g,
        (__attribute__((address_space(3))) void*)l, 16, 0, 0);
}

// ---------------------------------------------------------------------------
// prep: b1_all = [sb1 | b1_0 | b1_1] (fp32); addvec[e] init = b2_0 + b2_1;
// cnt = 0.
// ---------------------------------------------------------------------------
__global__ void prep_small(const float* __restrict__ sb1, const float* __restrict__ b1,
                           const float* __restrict__ b2,
                           float* __restrict__ b1_all, float* __restrict__ addvec,
                           int* __restrict__ cnt)
{
    int i = blockIdx.x * 256 + threadIdx.x;   // 0..12287
    b1_all[i] = (i < HIDDEN) ? sb1[i] : b1[i - HIDDEN];
    if (i < D_MODEL) {
        float s = b2[i] + b2[D_MODEL + i];
        addvec[i] = s;
        addvec[D_MODEL + i] = s;
    }
    if (i < 2) cnt[i] = 0;
}

// ---------------------------------------------------------------------------
// addvec[1-e][d] += sum_h relu(b1[e][h]) * w2[e][h][d]
// ---------------------------------------------------------------------------
__global__ void addvec_accum(const float* __restrict__ b1, const float* __restrict__ w2,
                             float* __restrict__ addvec)
{
    const int blk  = blockIdx.x;
    const int e    = blk >> 6;
    const int hseg = (blk >> 2) & 15;
    const int d    = (blk & 3) * 256 + threadIdx.x;
    const float* B1 = b1 + e * HIDDEN + hseg * 256;
    const float* W  = w2 + (size_t)e * HIDDEN * D_MODEL + (size_t)hseg * 256 * D_MODEL + d;
    float s = 0.f;
    for (int h = 0; h < 256; ++h) {
        float b = B1[h]; b = b > 0.f ? b : 0.f;
        s += b * W[(size_t)h * D_MODEL];
    }
    atomicAdd(&addvec[(1 - e) * D_MODEL + d], s);
}

// ---------------------------------------------------------------------------
// 32x32 tiled transpose + fp32->bf16 cast:  dst[c][r] = (bf16)src[r][c]
// ---------------------------------------------------------------------------
__global__ void transpose_cast(const float* __restrict__ src, bf16* __restrict__ dst,
                               int R, int Cc, int ldDst)
{
    __shared__ float tile[32][33];
    const int bx = blockIdx.x * 32;
    const int by = blockIdx.y * 32;
    const int tx = threadIdx.x & 31;
    const int ty = threadIdx.x >> 5;
#pragma unroll
    for (int i = 0; i < 32; i += 8)
        tile[ty + i][tx] = src[(size_t)(by + ty + i) * Cc + bx + tx];
    __syncthreads();
#pragma unroll
    for (int i = 0; i < 32; i += 8)
        dst[(size_t)(bx + ty + i) * ldDst + by + tx] = __float2bfloat16(tile[tx][ty + i]);
}

// ---------------------------------------------------------------------------
// Gating (fp32, argmax == softmax-top1) + x cast to bf16 + group position.
// ---------------------------------------------------------------------------
__global__ void gate_route_cast(const float* __restrict__ x, const float* __restrict__ gw,
                                int* __restrict__ route, int* __restrict__ pos,
                                int* __restrict__ cnt, bf16* __restrict__ Xb)
{
    const int token = blockIdx.x * 4 + (threadIdx.x >> 6);
    const int lane  = threadIdx.x & 63;
    const float4* xr = (const float4*)(x + (size_t)token * D_MODEL);
    const float4* g0 = (const float4*)gw;
    const float4* g1 = (const float4*)(gw + D_MODEL);
    bf16x4* xo = (bf16x4*)(Xb + (size_t)token * D_MODEL);
    float s0 = 0.f, s1 = 0.f;
    for (int i = lane; i < D_MODEL / 4; i += 64) {
        float4 v = xr[i];
        float4 a = g0[i], b = g1[i];
        s0 += v.x * a.x + v.y * a.y + v.z * a.z + v.w * a.w;
        s1 += v.x * b.x + v.y * b.y + v.z * b.z + v.w * b.w;
        bf16x4 o = { __float2bfloat16(v.x), __float2bfloat16(v.y),
                     __float2bfloat16(v.z), __float2bfloat16(v.w) };
        xo[i] = o;
    }
#pragma unroll
    for (int off = 32; off > 0; off >>= 1) {
        s0 += __shfl_down(s0, off, 64);
        s1 += __shfl_down(s1, off, 64);
    }
    if (lane == 0) {
        int r = (s1 > s0) ? 1 : 0;
        route[token] = r;
        pos[token] = atomicAdd(&cnt[r], 1);
    }
}

// gperm init + per-256-row-block expert id.  off1 = ceil(count0/256)*256.
__global__ void k_init(const int* __restrict__ cnt, int* __restrict__ gperm,
                       int* __restrict__ blkexp)
{
    int i = blockIdx.x * 256 + threadIdx.x;   // 0..GPAD-1
    int off1 = ((cnt[0] + 255) >> 8) << 8;
    if (i < GPAD) gperm[i] = -1;
    if (i < GPAD / 256) blkexp[i] = (i * 256 >= off1) ? 1 : 0;
}

__global__ void k_scatter(const int* __restrict__ route, const int* __restrict__ pos,
                          const int* __restrict__ cnt, int* __restrict__ gperm)
{
    int t = blockIdx.x * 256 + threadIdx.x;   // 0..NTOK-1
    int off1 = ((cnt[0] + 255) >> 8) << 8;
    int g = route[t] ? off1 + pos[t] : pos[t];
    gperm[g] = t;
}

// Xg[g] = Xb[gperm[g]] or 0.
__global__ void gather_xg(const bf16* __restrict__ Xb, const int* __restrict__ gperm,
                          bf16* __restrict__ Xg)
{
    const int g = blockIdx.x * 2 + (threadIdx.x >> 7);
    const int l = threadIdx.x & 127;
    const int t = gperm[g];
    float4* dst = (float4*)(Xg + (size_t)g * D_MODEL);
    if (t >= 0) {
        const float4* src = (const float4*)(Xb + (size_t)t * D_MODEL);
        dst[l] = src[l];
    } else {
        dst[l] = make_float4(0.f, 0.f, 0.f, 0.f);
    }
}

// ---------------------------------------------------------------------------
// 256x256 bf16 GEMM:  C[M,N] = A[M,K] @ B[N,K]^T (row stride ldb)
// BK=64, 8 waves (2Mx4N, each 128x64 out), 128 KiB LDS double buffer.
// Depth-2 pipeline: counted s_waitcnt vmcnt(8) across raw s_barriers (T4).
// LDS XOR-swizzle (T2) via pre-swizzled GLOBAL source + swizzled read.
// setprio around MFMA clusters (T5).
// NEW (R1): T1 bijective XCD-chunked block swizzle. HW round-robins original
// linear block id across the 8 XCDs; remap so each XCD owns a CONTIGUOUS
// range of output tiles (bx fastest) -> co-resident WGs on one XCD form
// ~2 M-rows x all N-cols -> per-K-tile panel working set ~576 KB fits the
// 4 MB per-XCD L2 -> A/B panels fetched once per XCD instead of per WG.
// MODE 0: shared GEMM1 -> H (bf16 relu);  MODE 1: shared GEMM2 -> out (fp32)
// MODE 2: grouped GEMM1 -> H;             MODE 3: grouped GEMM2 scatter-add
// ---------------------------------------------------------------------------
template <int MODE>
__global__ __launch_bounds__(512, 2) void gemm256(
    const bf16* __restrict__ A, const bf16* __restrict__ B,
    void* __restrict__ Cout, const float* __restrict__ bias,
    const int* __restrict__ blkexp, const int* __restrict__ gperm,
    int M, int N, int K, int ldb)
{
    __shared__ bf16 smem[2 * 2 * 16384];          // [buf][A|B][256*64] = 128 KiB
    (void)M;
    const int tid  = threadIdx.x;
    const int lane = tid & 63;
    const int wave = tid >> 6;

    // ---- T1: bijective XCD-chunked swizzle (m204 formula) ----------------
    // original id o lands on XCD (o & 7); give that XCD contiguous tiles.
    const int nwg = gridDim.x * gridDim.y;
    const int o   = blockIdx.y * gridDim.x + blockIdx.x;
    const int q   = nwg >> 3, r = nwg & 7;
    const int xcd = o & 7, idx = o >> 3;
    const int tile = (xcd < r ? xcd * (q + 1) : r * (q + 1) + (xcd - r) * q) + idx;
    const int bx2 = tile % gridDim.x;             // N block (fastest -> shares A)
    const int by2 = tile / gridDim.x;             // M block
    const long bm = (long)by2 * 256;
    const long bn = (long)bx2 * 256;

    long bOff = 0;
    const float* biasP = bias;
    int e = 0;
    if (MODE == 2) {
        e = blkexp[by2];
        bOff = (long)(1 + e) * HIDDEN * ldb;      // W1t expert row section
        biasP = bias + (1 + e) * HIDDEN;
    }
    if (MODE == 3) {
        e = blkexp[by2];
        bOff = (long)(1 + e) * HIDDEN;            // W2t expert col section
        biasP = bias + e * D_MODEL;
    }

    // ---- staging: linear LDS dest, pre-swizzled global source ------------
    const int p    = tid * 16;                        // linear byte in first 8KB slab
    const int sp   = p ^ (((p >> 7) & 7) << 4);       // involutive slot swizzle
    const int srow = sp >> 7;                         // 0..63
    const int sce  = (sp & 127) >> 1;                 // element col 0..63
    const bf16* sAp = A + (size_t)(bm + srow) * K + sce;
    const bf16* sBp = B + bOff + (size_t)(bn + srow) * ldb + sce;
    const size_t sAstep = (size_t)64 * K;             // +64 rows per instruction slab
    const size_t sBstep = (size_t)64 * ldb;
    bf16* ldsA = smem + wave * 512;                   // + buf*32768 + i*4096
    bf16* ldsB = smem + 16384 + wave * 512;

    // ---- fragment read addressing (swizzled) -----------------------------
    const int wm  = wave >> 2;                        // 0..1
    const int wn  = wave & 3;                         // 0..3
    const int fr  = lane & 15;
    const int fkb = (lane >> 4) << 4;                 // 0/16/32/48 bytes (8 K-elems)
    const int sx  = (fr & 7) << 4;                    // per-lane swizzle XOR
    const char* sb = (const char*)smem;
    const int aBase = (wm * 128 + fr) * 128;          // byte offset in A region
    const int bBase = 32768 + (wn * 64 + fr) * 128;   // byte offset in buf (B region)

    floatx4 acc[8][4];
#pragma unroll
    for (int i = 0; i < 8; i++)
#pragma unroll
        for (int j = 0; j < 4; j++) acc[i][j] = (floatx4){0.f, 0.f, 0.f, 0.f};

    const int NT = K >> 6;                            // 64-wide K tiles (>= 16 here)

#define STAGE(b) do {                                                         \
    _Pragma("unroll")                                                         \
    for (int i_ = 0; i_ < 4; ++i_) {                                          \
        gload_lds16(sAp + (size_t)i_ * sAstep, ldsA + (b) * 32768 + i_ * 4096); \
        gload_lds16(sBp + (size_t)i_ * sBstep, ldsB + (b) * 32768 + i_ * 4096); \
    }                                                                         \
    sAp += 64; sBp += 64;                                                     \
} while (0)

#define COMPUTE(b) do {                                                       \
    const char* cb_ = sb + (b) * 65536;                                       \
    _Pragma("unroll")                                                         \
    for (int ks_ = 0; ks_ < 2; ++ks_) {                                       \
        const int kx_ = ((ks_ * 64) + fkb) ^ sx;                              \
        short8 af_[8], bf_[4];                                                \
        _Pragma("unroll")                                                     \
        for (int i_ = 0; i_ < 8; ++i_)                                        \
            af_[i_] = *(const short8*)(cb_ + aBase + i_ * 2048 + kx_);        \
        _Pragma("unroll")                                                     \
        for (int j_ = 0; j_ < 4; ++j_)                                        \
            bf_[j_] = *(const short8*)(cb_ + bBase + j_ * 2048 + kx_);        \
        __builtin_amdgcn_s_setprio(1);                                        \
        _Pragma("unroll")                                                     \
        for (int i_ = 0; i_ < 8; ++i_) {                                      \
            _Pragma("unroll")                                                 \
            for (int j_ = 0; j_ < 4; ++j_)                                    \
                acc[i_][j_] = __builtin_amdgcn_mfma_f32_16x16x32_bf16(        \
                    af_[i_], bf_[j_], acc[i_][j_], 0, 0, 0);                  \
        }                                                                     \
        __builtin_amdgcn_s_setprio(0);                                        \
    }                                                                         \
} while (0)

    STAGE(0);                                         // tile 0 -> buf0
    STAGE(1);                                         // tile 1 -> buf1  (16 loads in flight)

    for (int t = 0; t < NT - 2; ++t) {
        asm volatile("s_waitcnt vmcnt(8)" ::: "memory");   // tile t landed (own slice)
        __builtin_amdgcn_s_barrier();                      // ...and everyone else's
        __builtin_amdgcn_sched_barrier(0);
        COMPUTE(t & 1);
        __builtin_amdgcn_sched_barrier(0);
        __builtin_amdgcn_s_barrier();                      // all waves done reading buf
        STAGE(t & 1);                                      // tile t+2 overwrites it
    }
    asm volatile("s_waitcnt vmcnt(8)" ::: "memory");
    __builtin_amdgcn_s_barrier();
    __builtin_amdgcn_sched_barrier(0);
    COMPUTE(NT & 1);                                       // tile NT-2
    asm volatile("s_waitcnt vmcnt(0)" ::: "memory");
    __builtin_amdgcn_s_barrier();
    __builtin_amdgcn_sched_barrier(0);
    COMPUTE((NT - 1) & 1);                                 // tile NT-1

#undef STAGE
#undef COMPUTE

    // epilogue: C/D layout col = lane&15, row = (lane>>4)*4 + reg
    const int rq = (lane >> 4) * 4;
#pragma unroll
    for (int j = 0; j < 4; ++j) {
        const long col = bn + wn * 64 + j * 16 + fr;
        const float bv = biasP[col];
#pragma unroll
        for (int i = 0; i < 8; ++i) {
#pragma unroll
            for (int r2 = 0; r2 < 4; ++r2) {
                const long row = bm + wm * 128 + i * 16 + rq + r2;
                float v = acc[i][j][r2] + bv;
                if (MODE == 0 || MODE == 2) {
                    v = v > 0.f ? v : 0.f;
                    ((bf16*)Cout)[row * (long)N + col] = __float2bfloat16(v);
                } else if (MODE == 1) {
                    ((float*)Cout)[row * (long)N + col] = v;
                } else {   // MODE 3: scatter-add
                    const int tt = gperm[row];
                    if (tt >= 0) {
                        float* o2 = (float*)Cout + (size_t)tt * D_MODEL + col;
                        *o2 += v;
                    }
                }
            }
        }
    }
}

// ---------------------------------------------------------------------------
extern "C" void kernel_launch(void* const* d_in, const int* in_sizes, int n_in,
                              void* d_out, int out_size, void* d_ws, size_t ws_size,
                              hipStream_t stream)
{
    const float* x   = (const float*)d_in[0];
    const float* gw  = (const float*)d_in[1];
    const float* w1  = (const float*)d_in[2];   // [2, 1024, 4096]
    const float* b1  = (const float*)d_in[3];   // [2, 4096]
    const float* w2  = (const float*)d_in[4];   // [2, 4096, 1024]
    const float* b2  = (const float*)d_in[5];   // [2, 1024]
    const float* sw1 = (const float*)d_in[6];   // [1024, 4096]
    const float* sb1 = (const float*)d_in[7];
    const float* sw2 = (const float*)d_in[8];   // [4096, 1024]
    const float* sb2 = (const float*)d_in[9];
    float* out = (float*)d_out;

    // ---- workspace carve-up ---------------------------------------------
    char* p = (char*)d_ws;
    bf16* Xb      = (bf16*)p;  p += (size_t)NTOK * D_MODEL * 2;    // 32 MB
    bf16* Xg      = (bf16*)p;  p += (size_t)GPAD * D_MODEL * 2;    // 32.5 MB
    bf16* W1t     = (bf16*)p;  p += (size_t)HP * D_MODEL * 2;      // 24 MB  [HP,1024]
    bf16* W2t     = (bf16*)p;  p += (size_t)D_MODEL * HP * 2;      // 24 MB  [1024,HP]
    int*  route   = (int*)p;   p += (size_t)NTOK * 4;
    int*  pos     = (int*)p;   p += (size_t)NTOK * 4;
    int*  gperm   = (int*)p;   p += (size_t)GPAD * 4;
    int*  blkexp  = (int*)p;   p += (size_t)(GPAD / 128) * 4;
    int*  cnt     = (int*)p;   p += 2 * 4;
    float* b1_all = (float*)p; p += (size_t)HP * 4;
    float* addvec = (float*)p; p += (size_t)2 * D_MODEL * 4;
    bf16* H       = (bf16*)p;                                      // rest

    const size_t used_fixed = (size_t)(p - (char*)d_ws);
    const size_t avail = (ws_size > used_fixed) ? (ws_size - used_fixed) : 0;
    long cs = (long)(avail / ((size_t)HIDDEN * 2));   // tokens per H chunk
    cs = (cs / 256) * 256;
    if (cs > GPAD) cs = GPAD;
    if (cs < 256) cs = 256;

    prep_small<<<HP / 256, 256, 0, stream>>>(sb1, b1, b2, b1_all, addvec, cnt);
    addvec_accum<<<128, 256, 0, stream>>>(b1, w2, addvec);

    // W1t rows h: [0,4096)=shared, [4096,8192)=e0, [8192,12288)=e1 ; ld 1024
    transpose_cast<<<dim3(HIDDEN / 32, D_MODEL / 32), 256, 0, stream>>>(
        sw1, W1t, D_MODEL, HIDDEN, D_MODEL);
    transpose_cast<<<dim3(HIDDEN / 32, D_MODEL / 32), 256, 0, stream>>>(
        w1, W1t + (size_t)HIDDEN * D_MODEL, D_MODEL, HIDDEN, D_MODEL);
    transpose_cast<<<dim3(HIDDEN / 32, D_MODEL / 32), 256, 0, stream>>>(
        w1 + (size_t)D_MODEL * HIDDEN, W1t + (size_t)2 * HIDDEN * D_MODEL, D_MODEL, HIDDEN, D_MODEL);
    // W2t [1024 rows, ld HP]: cols [0,4096)=shared, then e0, e1
    transpose_cast<<<dim3(D_MODEL / 32, HIDDEN / 32), 256, 0, stream>>>(
        sw2, W2t, HIDDEN, D_MODEL, HP);
    transpose_cast<<<dim3(D_MODEL / 32, HIDDEN / 32), 256, 0, stream>>>(
        w2, W2t + HIDDEN, HIDDEN, D_MODEL, HP);
    transpose_cast<<<dim3(D_MODEL / 32, HIDDEN / 32), 256, 0, stream>>>(
        w2 + (size_t)HIDDEN * D_MODEL, W2t + (size_t)2 * HIDDEN, HIDDEN, D_MODEL, HP);

    gate_route_cast<<<NTOK / 4, 256, 0, stream>>>(x, gw, route, pos, cnt, Xb);
    k_init<<<(GPAD + 255) / 256, 256, 0, stream>>>(cnt, gperm, blkexp);
    k_scatter<<<NTOK / 256, 256, 0, stream>>>(route, pos, cnt, gperm);
    gather_xg<<<GPAD / 2, 256, 0, stream>>>(Xb, gperm, Xg);

    // ---- shared FFN over all tokens (writes out = shared + sb2) ----------
    for (long t0 = 0; t0 < NTOK; t0 += cs) {
        const long cur = (NTOK - t0 < cs) ? (NTOK - t0) : cs;
        gemm256<0><<<dim3(HIDDEN / 256, cur / 256), 512, 0, stream>>>(
            Xb + t0 * D_MODEL, W1t, H, b1_all, nullptr, nullptr,
            (int)cur, HIDDEN, D_MODEL, D_MODEL);
        gemm256<1><<<dim3(D_MODEL / 256, cur / 256), 512, 0, stream>>>(
            H, W2t, out + t0 * D_MODEL, sb2, nullptr, nullptr,
            (int)cur, D_MODEL, HIDDEN, HP);
    }
    // ---- routed expert over grouped tokens (scatter-add) -----------------
    for (long g0 = 0; g0 < GPAD; g0 += cs) {
        const long cur = (GPAD - g0 < cs) ? (GPAD - g0) : cs;
        gemm256<2><<<dim3(HIDDEN / 256, cur / 256), 512, 0, stream>>>(
            Xg + g0 * D_MODEL, W1t, H, b1_all, blkexp + g0 / 256, nullptr,
            (int)cur, HIDDEN, D_MODEL, D_MODEL);
        gemm256<3><<<dim3(D_MODEL / 256, cur / 256), 512, 0, stream>>>(
            H, W2t, (void*)out, addvec, blkexp + g0 / 256, gperm + g0,
            (int)cur, D_MODEL, HIDDEN, HP);
    }
}

// Round 3
// 1249.994 us; speedup vs baseline: 1.0782x; 1.0593x over previous
//
#include <hip/hip_runtime.h>
#include <hip/hip_bf16.h>

#define D_MODEL 1024
#define HIDDEN  4096
#define NTOK    16384
#define HP      12288   // shared + expert0 + expert1 hidden rows in W1t / cols in W2t
#define GPAD    16640   // 65 * 256 padded grouped-token space (256-granular)

typedef __hip_bfloat16 bf16;
typedef __attribute__((ext_vector_type(8))) short short8;
typedef __attribute__((ext_vector_type(4))) float floatx4;

struct bf16x4 { bf16 a, b, c, d; };

__device__ inline void gload_lds16(const bf16* g, bf16* l) {
    __builtin_amdgcn_global_load_lds(
        (const __attribute__((address_space(1))) void*)g,
        (__attribute__((address_space(3))) void*)l, 16, 0, 0);
}

// ---------------------------------------------------------------------------
// prep: b1_all = [sb1 | b1_0 | b1_1] (fp32); addvec[e] init = b2_0 + b2_1;
// cnt = 0.
// ---------------------------------------------------------------------------
__global__ void prep_small(const float* __restrict__ sb1, const float* __restrict__ b1,
                           const float* __restrict__ b2,
                           float* __restrict__ b1_all, float* __restrict__ addvec,
                           int* __restrict__ cnt)
{
    int i = blockIdx.x * 256 + threadIdx.x;   // 0..12287
    b1_all[i] = (i < HIDDEN) ? sb1[i] : b1[i - HIDDEN];
    if (i < D_MODEL) {
        float s = b2[i] + b2[D_MODEL + i];
        addvec[i] = s;
        addvec[D_MODEL + i] = s;
    }
    if (i < 2) cnt[i] = 0;
}

// ---------------------------------------------------------------------------
// addvec[1-e][d] += sum_h relu(b1[e][h]) * w2[e][h][d]
// ---------------------------------------------------------------------------
__global__ void addvec_accum(const float* __restrict__ b1, const float* __restrict__ w2,
                             float* __restrict__ addvec)
{
    const int blk  = blockIdx.x;
    const int e    = blk >> 6;
    const int hseg = (blk >> 2) & 15;
    const int d    = (blk & 3) * 256 + threadIdx.x;
    const float* B1 = b1 + e * HIDDEN + hseg * 256;
    const float* W  = w2 + (size_t)e * HIDDEN * D_MODEL + (size_t)hseg * 256 * D_MODEL + d;
    float s = 0.f;
    for (int h = 0; h < 256; ++h) {
        float b = B1[h]; b = b > 0.f ? b : 0.f;
        s += b * W[(size_t)h * D_MODEL];
    }
    atomicAdd(&addvec[(1 - e) * D_MODEL + d], s);
}

// ---------------------------------------------------------------------------
// 32x32 tiled transpose + fp32->bf16 cast:  dst[c][r] = (bf16)src[r][c]
// ---------------------------------------------------------------------------
__global__ void transpose_cast(const float* __restrict__ src, bf16* __restrict__ dst,
                               int R, int Cc, int ldDst)
{
    __shared__ float tile[32][33];
    const int bx = blockIdx.x * 32;
    const int by = blockIdx.y * 32;
    const int tx = threadIdx.x & 31;
    const int ty = threadIdx.x >> 5;
#pragma unroll
    for (int i = 0; i < 32; i += 8)
        tile[ty + i][tx] = src[(size_t)(by + ty + i) * Cc + bx + tx];
    __syncthreads();
#pragma unroll
    for (int i = 0; i < 32; i += 8)
        dst[(size_t)(bx + ty + i) * ldDst + by + tx] = __float2bfloat16(tile[tx][ty + i]);
}

// ---------------------------------------------------------------------------
// Gating (fp32, argmax == softmax-top1) + x cast to bf16 + group position.
// ---------------------------------------------------------------------------
__global__ void gate_route_cast(const float* __restrict__ x, const float* __restrict__ gw,
                                int* __restrict__ route, int* __restrict__ pos,
                                int* __restrict__ cnt, bf16* __restrict__ Xb)
{
    const int token = blockIdx.x * 4 + (threadIdx.x >> 6);
    const int lane  = threadIdx.x & 63;
    const float4* xr = (const float4*)(x + (size_t)token * D_MODEL);
    const float4* g0 = (const float4*)gw;
    const float4* g1 = (const float4*)(gw + D_MODEL);
    bf16x4* xo = (bf16x4*)(Xb + (size_t)token * D_MODEL);
    float s0 = 0.f, s1 = 0.f;
    for (int i = lane; i < D_MODEL / 4; i += 64) {
        float4 v = xr[i];
        float4 a = g0[i], b = g1[i];
        s0 += v.x * a.x + v.y * a.y + v.z * a.z + v.w * a.w;
        s1 += v.x * b.x + v.y * b.y + v.z * b.z + v.w * b.w;
        bf16x4 o = { __float2bfloat16(v.x), __float2bfloat16(v.y),
                     __float2bfloat16(v.z), __float2bfloat16(v.w) };
        xo[i] = o;
    }
#pragma unroll
    for (int off = 32; off > 0; off >>= 1) {
        s0 += __shfl_down(s0, off, 64);
        s1 += __shfl_down(s1, off, 64);
    }
    if (lane == 0) {
        int r = (s1 > s0) ? 1 : 0;
        route[token] = r;
        pos[token] = atomicAdd(&cnt[r], 1);
    }
}

// gperm init + per-256-row-block expert id.  off1 = ceil(count0/256)*256.
__global__ void k_init(const int* __restrict__ cnt, int* __restrict__ gperm,
                       int* __restrict__ blkexp)
{
    int i = blockIdx.x * 256 + threadIdx.x;   // 0..GPAD-1
    int off1 = ((cnt[0] + 255) >> 8) << 8;
    if (i < GPAD) gperm[i] = -1;
    if (i < GPAD / 256) blkexp[i] = (i * 256 >= off1) ? 1 : 0;
}

__global__ void k_scatter(const int* __restrict__ route, const int* __restrict__ pos,
                          const int* __restrict__ cnt, int* __restrict__ gperm)
{
    int t = blockIdx.x * 256 + threadIdx.x;   // 0..NTOK-1
    int off1 = ((cnt[0] + 255) >> 8) << 8;
    int g = route[t] ? off1 + pos[t] : pos[t];
    gperm[g] = t;
}

// Xg[g] = Xb[gperm[g]] or 0.
__global__ void gather_xg(const bf16* __restrict__ Xb, const int* __restrict__ gperm,
                          bf16* __restrict__ Xg)
{
    const int g = blockIdx.x * 2 + (threadIdx.x >> 7);
    const int l = threadIdx.x & 127;
    const int t = gperm[g];
    float4* dst = (float4*)(Xg + (size_t)g * D_MODEL);
    if (t >= 0) {
        const float4* src = (const float4*)(Xb + (size_t)t * D_MODEL);
        dst[l] = src[l];
    } else {
        dst[l] = make_float4(0.f, 0.f, 0.f, 0.f);
    }
}

// ---------------------------------------------------------------------------
// 256x256 bf16 GEMM:  C[M,N] = A[M,K] @ B[N,K]^T (row stride ldb)
// BK=64, 8 waves (2Mx4N, each 128x64 out), 128 KiB LDS double buffer.
// R3: m201-style 8-phase schedule (T3+T4). Per K-tile, 4 phases:
//   phase(ks,mh): { ds_read 4-8 b128 (B[ks] if mh==0, A[mh,ks]) ;
//                   stage next K-tile (A in ph1, B in ph2, into OTHER buf) ;
//                   barrier ; lgkmcnt(0)+sched_barrier ;
//                   setprio(1) ; 16 MFMA (quadrant mh x ks) ; setprio(0) ;
//                   [ph4: vmcnt(0) -- operands issued >=2 phases ago] ;
//                   barrier }
// T1 bijective XCD-chunked swizzle (kept: FETCH 553->160 MB measured).
// T2 LDS swizzle via pre-swizzled global source + XOR'd read (0 conflicts).
// MODE 0: shared GEMM1 -> H (bf16 relu);  MODE 1: shared GEMM2 -> out (fp32)
// MODE 2: grouped GEMM1 -> H;             MODE 3: grouped GEMM2 scatter-add
// ---------------------------------------------------------------------------
template <int MODE>
__global__ __launch_bounds__(512, 2) void gemm256(
    const bf16* __restrict__ A, const bf16* __restrict__ B,
    void* __restrict__ Cout, const float* __restrict__ bias,
    const int* __restrict__ blkexp, const int* __restrict__ gperm,
    int M, int N, int K, int ldb)
{
    __shared__ bf16 smem[2 * 2 * 16384];          // [buf][A|B][256*64] = 128 KiB
    (void)M;
    const int tid  = threadIdx.x;
    const int lane = tid & 63;
    const int wave = tid >> 6;

    // ---- T1: bijective XCD-chunked swizzle (m204 formula) ----------------
    const int nwg = gridDim.x * gridDim.y;
    const int o   = blockIdx.y * gridDim.x + blockIdx.x;
    const int q   = nwg >> 3, r = nwg & 7;
    const int xcd = o & 7, idx = o >> 3;
    const int tile = (xcd < r ? xcd * (q + 1) : r * (q + 1) + (xcd - r) * q) + idx;
    const int bx2 = tile % gridDim.x;             // N block (fastest -> shares A)
    const int by2 = tile / gridDim.x;             // M block
    const long bm = (long)by2 * 256;
    const long bn = (long)bx2 * 256;

    long bOff = 0;
    const float* biasP = bias;
    int e = 0;
    if (MODE == 2) {
        e = blkexp[by2];
        bOff = (long)(1 + e) * HIDDEN * ldb;      // W1t expert row section
        biasP = bias + (1 + e) * HIDDEN;
    }
    if (MODE == 3) {
        e = blkexp[by2];
        bOff = (long)(1 + e) * HIDDEN;            // W2t expert col section
        biasP = bias + e * D_MODEL;
    }

    // ---- staging: linear LDS dest, pre-swizzled global source ------------
    const int p    = tid * 16;                        // linear byte in first 8KB slab
    const int sp   = p ^ (((p >> 7) & 7) << 4);       // involutive slot swizzle
    const int srow = sp >> 7;                         // 0..63
    const int sce  = (sp & 127) >> 1;                 // element col 0..63
    const bf16* sAp = A + (size_t)(bm + srow) * K + sce;
    const bf16* sBp = B + bOff + (size_t)(bn + srow) * ldb + sce;
    const size_t sAstep = (size_t)64 * K;             // +64 rows per instruction slab
    const size_t sBstep = (size_t)64 * ldb;
    bf16* ldsA = smem + wave * 512;                   // + buf*32768 + i*4096
    bf16* ldsB = smem + 16384 + wave * 512;

    // ---- fragment read addressing (swizzled) -----------------------------
    const int wm  = wave >> 2;                        // 0..1
    const int wn  = wave & 3;                         // 0..3
    const int fr  = lane & 15;
    const int fkb = (lane >> 4) << 4;                 // 0/16/32/48 bytes (8 K-elems)
    const int sx  = (fr & 7) << 4;                    // per-lane swizzle XOR
    const char* sb = (const char*)smem;
    const int aBase = (wm * 128 + fr) * 128;          // byte offset in A region
    const int bBase = 32768 + (wn * 64 + fr) * 128;   // byte offset in buf (B region)

    floatx4 acc[8][4];
#pragma unroll
    for (int i = 0; i < 8; i++)
#pragma unroll
        for (int j = 0; j < 4; j++) acc[i][j] = (floatx4){0.f, 0.f, 0.f, 0.f};

    const int NT = K >> 6;                            // 64-wide K tiles

#define STAGE_A(b) do {                                                        \
    _Pragma("unroll")                                                          \
    for (int i_ = 0; i_ < 4; ++i_)                                             \
        gload_lds16(sAp + (size_t)i_ * sAstep, ldsA + (b) * 32768 + i_ * 4096);\
    sAp += 64;                                                                 \
} while (0)

#define STAGE_B(b) do {                                                        \
    _Pragma("unroll")                                                          \
    for (int i_ = 0; i_ < 4; ++i_)                                             \
        gload_lds16(sBp + (size_t)i_ * sBstep, ldsB + (b) * 32768 + i_ * 4096);\
    sBp += 64;                                                                 \
} while (0)

// One phase: quadrant (mh) of K-sub-step (ks). Reads B frags only when mh==0
// (they persist to the mh==1 phase). 16 MFMA per phase.
#define PHASE(ks, mh, STAGE_STMT, TAILWAIT) do {                               \
    const int kx_ = ((ks) * 64 + fkb) ^ sx;                                    \
    if ((mh) == 0) {                                                           \
        _Pragma("unroll")                                                      \
        for (int nf_ = 0; nf_ < 4; ++nf_)                                      \
            bfr[nf_] = *(const short8*)(cb + bBase + nf_ * 2048 + kx_);        \
    }                                                                          \
    _Pragma("unroll")                                                          \
    for (int mf_ = 0; mf_ < 4; ++mf_)                                          \
        afr[mf_] = *(const short8*)(cb + aBase + (mh) * 8192 + mf_ * 2048 + kx_);\
    STAGE_STMT;                                                                \
    __builtin_amdgcn_s_barrier();                                              \
    asm volatile("s_waitcnt lgkmcnt(0)" ::: "memory");                         \
    __builtin_amdgcn_sched_barrier(0);                                         \
    __builtin_amdgcn_s_setprio(1);                                             \
    _Pragma("unroll")                                                          \
    for (int mf_ = 0; mf_ < 4; ++mf_)                                          \
        _Pragma("unroll")                                                      \
        for (int nf_ = 0; nf_ < 4; ++nf_)                                      \
            acc[(mh) * 4 + mf_][nf_] = __builtin_amdgcn_mfma_f32_16x16x32_bf16(\
                afr[mf_], bfr[nf_], acc[(mh) * 4 + mf_][nf_], 0, 0, 0);        \
    __builtin_amdgcn_s_setprio(0);                                             \
    TAILWAIT;                                                                  \
    __builtin_amdgcn_s_barrier();                                              \
} while (0)

    short8 afr[4], bfr[4];

    // prologue: K-tile 0 -> buf0; one-time drain (cost ~1 load latency)
    STAGE_A(0);
    STAGE_B(0);
    asm volatile("s_waitcnt vmcnt(0)" ::: "memory");
    __builtin_amdgcn_s_barrier();

    for (int kt = 0; kt < NT; ++kt) {
        const int buf = kt & 1, nbuf = buf ^ 1;
        const char* cb = sb + buf * 65536;
        const bool more = (kt + 1 < NT);
        // staging of K-tile kt+1 goes into nbuf, whose last readers (K-tile
        // kt-1) all passed the previous phase-4 barrier -> race-free.
        PHASE(0, 0, if (more) STAGE_A(nbuf), );
        PHASE(0, 1, if (more) STAGE_B(nbuf), );
        PHASE(1, 0, , );
        PHASE(1, 1, ,
              asm volatile("s_waitcnt vmcnt(0)" ::: "memory"));
        // vmcnt(0) above waits on loads issued >=2 phases (~1500+ cyc) ago:
        // non-stalling in steady state, and guarantees buf[nbuf] is fully
        // landed before any wave's phase-1 ds_read of the next K-tile.
    }

#undef STAGE_A
#undef STAGE_B
#undef PHASE

    // epilogue: C/D layout col = lane&15, row = (lane>>4)*4 + reg
    const int rq = (lane >> 4) * 4;
#pragma unroll
    for (int j = 0; j < 4; ++j) {
        const long col = bn + wn * 64 + j * 16 + fr;
        const float bv = biasP[col];
#pragma unroll
        for (int i = 0; i < 8; ++i) {
#pragma unroll
            for (int r2 = 0; r2 < 4; ++r2) {
                const long row = bm + wm * 128 + i * 16 + rq + r2;
                float v = acc[i][j][r2] + bv;
                if (MODE == 0 || MODE == 2) {
                    v = v > 0.f ? v : 0.f;
                    ((bf16*)Cout)[row * (long)N + col] = __float2bfloat16(v);
                } else if (MODE == 1) {
                    ((float*)Cout)[row * (long)N + col] = v;
                } else {   // MODE 3: scatter-add
                    const int tt = gperm[row];
                    if (tt >= 0) {
                        float* o2 = (float*)Cout + (size_t)tt * D_MODEL + col;
                        *o2 += v;
                    }
                }
            }
        }
    }
}

// ---------------------------------------------------------------------------
extern "C" void kernel_launch(void* const* d_in, const int* in_sizes, int n_in,
                              void* d_out, int out_size, void* d_ws, size_t ws_size,
                              hipStream_t stream)
{
    const float* x   = (const float*)d_in[0];
    const float* gw  = (const float*)d_in[1];
    const float* w1  = (const float*)d_in[2];   // [2, 1024, 4096]
    const float* b1  = (const float*)d_in[3];   // [2, 4096]
    const float* w2  = (const float*)d_in[4];   // [2, 4096, 1024]
    const float* b2  = (const float*)d_in[5];   // [2, 1024]
    const float* sw1 = (const float*)d_in[6];   // [1024, 4096]
    const float* sb1 = (const float*)d_in[7];
    const float* sw2 = (const float*)d_in[8];   // [4096, 1024]
    const float* sb2 = (const float*)d_in[9];
    float* out = (float*)d_out;

    // ---- workspace carve-up ---------------------------------------------
    char* p = (char*)d_ws;
    bf16* Xb      = (bf16*)p;  p += (size_t)NTOK * D_MODEL * 2;    // 32 MB
    bf16* Xg      = (bf16*)p;  p += (size_t)GPAD * D_MODEL * 2;    // 32.5 MB
    bf16* W1t     = (bf16*)p;  p += (size_t)HP * D_MODEL * 2;      // 24 MB  [HP,1024]
    bf16* W2t     = (bf16*)p;  p += (size_t)D_MODEL * HP * 2;      // 24 MB  [1024,HP]
    int*  route   = (int*)p;   p += (size_t)NTOK * 4;
    int*  pos     = (int*)p;   p += (size_t)NTOK * 4;
    int*  gperm   = (int*)p;   p += (size_t)GPAD * 4;
    int*  blkexp  = (int*)p;   p += (size_t)(GPAD / 128) * 4;
    int*  cnt     = (int*)p;   p += 2 * 4;
    float* b1_all = (float*)p; p += (size_t)HP * 4;
    float* addvec = (float*)p; p += (size_t)2 * D_MODEL * 4;
    bf16* H       = (bf16*)p;                                      // rest

    const size_t used_fixed = (size_t)(p - (char*)d_ws);
    const size_t avail = (ws_size > used_fixed) ? (ws_size - used_fixed) : 0;
    long cs = (long)(avail / ((size_t)HIDDEN * 2));   // tokens per H chunk
    cs = (cs / 256) * 256;
    if (cs > GPAD) cs = GPAD;
    if (cs < 256) cs = 256;

    prep_small<<<HP / 256, 256, 0, stream>>>(sb1, b1, b2, b1_all, addvec, cnt);
    addvec_accum<<<128, 256, 0, stream>>>(b1, w2, addvec);

    // W1t rows h: [0,4096)=shared, [4096,8192)=e0, [8192,12288)=e1 ; ld 1024
    transpose_cast<<<dim3(HIDDEN / 32, D_MODEL / 32), 256, 0, stream>>>(
        sw1, W1t, D_MODEL, HIDDEN, D_MODEL);
    transpose_cast<<<dim3(HIDDEN / 32, D_MODEL / 32), 256, 0, stream>>>(
        w1, W1t + (size_t)HIDDEN * D_MODEL, D_MODEL, HIDDEN, D_MODEL);
    transpose_cast<<<dim3(HIDDEN / 32, D_MODEL / 32), 256, 0, stream>>>(
        w1 + (size_t)D_MODEL * HIDDEN, W1t + (size_t)2 * HIDDEN * D_MODEL, D_MODEL, HIDDEN, D_MODEL);
    // W2t [1024 rows, ld HP]: cols [0,4096)=shared, then e0, e1
    transpose_cast<<<dim3(D_MODEL / 32, HIDDEN / 32), 256, 0, stream>>>(
        sw2, W2t, HIDDEN, D_MODEL, HP);
    transpose_cast<<<dim3(D_MODEL / 32, HIDDEN / 32), 256, 0, stream>>>(
        w2, W2t + HIDDEN, HIDDEN, D_MODEL, HP);
    transpose_cast<<<dim3(D_MODEL / 32, HIDDEN / 32), 256, 0, stream>>>(
        w2 + (size_t)HIDDEN * D_MODEL, W2t + (size_t)2 * HIDDEN, HIDDEN, D_MODEL, HP);

    gate_route_cast<<<NTOK / 4, 256, 0, stream>>>(x, gw, route, pos, cnt, Xb);
    k_init<<<(GPAD + 255) / 256, 256, 0, stream>>>(cnt, gperm, blkexp);
    k_scatter<<<NTOK / 256, 256, 0, stream>>>(route, pos, cnt, gperm);
    gather_xg<<<GPAD / 2, 256, 0, stream>>>(Xb, gperm, Xg);

    // ---- shared FFN over all tokens (writes out = shared + sb2) ----------
    for (long t0 = 0; t0 < NTOK; t0 += cs) {
        const long cur = (NTOK - t0 < cs) ? (NTOK - t0) : cs;
        gemm256<0><<<dim3(HIDDEN / 256, cur / 256), 512, 0, stream>>>(
            Xb + t0 * D_MODEL, W1t, H, b1_all, nullptr, nullptr,
            (int)cur, HIDDEN, D_MODEL, D_MODEL);
        gemm256<1><<<dim3(D_MODEL / 256, cur / 256), 512, 0, stream>>>(
            H, W2t, out + t0 * D_MODEL, sb2, nullptr, nullptr,
            (int)cur, D_MODEL, HIDDEN, HP);
    }
    // ---- routed expert over grouped tokens (scatter-add) -----------------
    for (long g0 = 0; g0 < GPAD; g0 += cs) {
        const long cur = (GPAD - g0 < cs) ? (GPAD - g0) : cs;
        gemm256<2><<<dim3(HIDDEN / 256, cur / 256), 512, 0, stream>>>(
            Xg + g0 * D_MODEL, W1t, H, b1_all, blkexp + g0 / 256, nullptr,
            (int)cur, HIDDEN, D_MODEL, D_MODEL);
        gemm256<3><<<dim3(D_MODEL / 256, cur / 256), 512, 0, stream>>>(
            H, W2t, (void*)out, addvec, blkexp + g0 / 256, gperm + g0,
            (int)cur, D_MODEL, HIDDEN, HP);
    }
}